// Round 1
// baseline (10.133 us; speedup 1.0000x reference)
//
#include <hip/hip_runtime.h>
#include <hip/hip_bf16.h>

// Embedding lookup: out[row, :] = weight[x[row], :]
// x: 8192 int32 indices, weight: 32000 x 128 f32, out: 8192 x 128 f32.
// One float4 (4 floats) per thread -> 32 threads per row, fully coalesced.

__global__ __launch_bounds__(256) void embedding_gather_kernel(
    const int* __restrict__ x,
    const float* __restrict__ weight,
    float* __restrict__ out,
    int n_rows) {
    int tid = blockIdx.x * blockDim.x + threadIdx.x;
    int row = tid >> 5;   // 32 threads per row (128 floats / 4 per thread)
    int col = tid & 31;
    if (row >= n_rows) return;

    int idx = x[row];
    const float4* src = reinterpret_cast<const float4*>(weight + (size_t)idx * 128);
    float4* dst = reinterpret_cast<float4*>(out + (size_t)row * 128);
    dst[col] = src[col];
}

extern "C" void kernel_launch(void* const* d_in, const int* in_sizes, int n_in,
                              void* d_out, int out_size, void* d_ws, size_t ws_size,
                              hipStream_t stream) {
    const int*   x      = (const int*)d_in[0];     // (2, 4096) int32 -> 8192 flat
    const float* weight = (const float*)d_in[1];   // (32000, 128) f32
    float*       out    = (float*)d_out;           // (2, 4096, 128) f32

    int n_rows = in_sizes[0];                      // 8192
    int total_threads = n_rows * 32;
    int block = 256;
    int grid = (total_threads + block - 1) / block;

    embedding_gather_kernel<<<grid, block, 0, stream>>>(x, weight, out, n_rows);
}

// Round 2
// 10.125 us; speedup vs baseline: 1.0008x; 1.0008x over previous
//
#include <hip/hip_runtime.h>
#include <hip/hip_bf16.h>

// Embedding lookup: out[row, :] = weight[x[row], :]
// x: 8192 int32 indices, weight: 32000 x 128 f32, out: 8192 x 128 f32.
// 32 threads per row (float4 each). Each thread services 2 rows (row, row+half)
// so the index-load -> row-load dependent chain overlaps 2-deep per lane (MLP=2).

__global__ __launch_bounds__(256) void embedding_gather_kernel(
    const int* __restrict__ x,
    const float* __restrict__ weight,
    float* __restrict__ out,
    int n_rows) {
    int tid  = blockIdx.x * blockDim.x + threadIdx.x;
    int slot = tid >> 5;          // row slot; handles 2 rows
    int col  = tid & 31;          // float4 index within the 128-float row
    int half = n_rows >> 1;       // 4096
    if (slot >= half) return;

    int r0 = slot;
    int r1 = slot + half;

    // Two independent index loads (one vmcnt group)
    int i0 = x[r0];
    int i1 = x[r1];

    const float4* w = reinterpret_cast<const float4*>(weight);
    // Two independent row-gather loads
    float4 v0 = w[(size_t)i0 * 32 + col];
    float4 v1 = w[(size_t)i1 * 32 + col];

    float4* o = reinterpret_cast<float4*>(out);
    o[(size_t)r0 * 32 + col] = v0;
    o[(size_t)r1 * 32 + col] = v1;
}

extern "C" void kernel_launch(void* const* d_in, const int* in_sizes, int n_in,
                              void* d_out, int out_size, void* d_ws, size_t ws_size,
                              hipStream_t stream) {
    const int*   x      = (const int*)d_in[0];     // (2, 4096) int32 -> 8192 flat
    const float* weight = (const float*)d_in[1];   // (32000, 128) f32
    float*       out    = (float*)d_out;           // (2, 4096, 128) f32

    int n_rows = in_sizes[0];                      // 8192
    int half   = n_rows >> 1;                      // 4096 row-slots
    int total_threads = half * 32;                 // 131072
    int block = 256;
    int grid  = (total_threads + block - 1) / block;   // 512 blocks

    embedding_gather_kernel<<<grid, block, 0, stream>>>(x, weight, out, n_rows);
}